// Round 2
// baseline (266.447 us; speedup 1.0000x reference)
//
#include <hip/hip_runtime.h>

// LocallyConnected2d: out[i,j] = sum_{kh,kw} x[i+kh, j+kw] * W[i,j,kh,kw]
// x: (450,450) f32 (810 KB, cache-resident, ~225x reuse),
// W: (436,436,15,15) f32 (171 MB, streamed exactly once)  -> HBM-bound,
// floor = 171MB / 6.3 TB/s ~= 27 us.
//
// R2 design: THREAD-per-output (R1 was wave-per-output + shuffle reduce).
//  - Each thread reads its 225 contiguous W floats sequentially. Adjacent
//    lanes are 900 B apart, so each load instruction touches 64 cache lines,
//    but each line is consumed 16x by the same lane over consecutive
//    iterations -> L1 absorbs the re-touches, HBM fetches each line once.
//  - x loads are stride-1 across lanes (coalesced) and L1/L2 hits.
//  - No reduction, no masked lanes, coalesced stores.
//  - kh-loop unrolled by 3 -> 45-load batches for latency hiding at the
//    grid's ~2.9 waves/SIMD occupancy.

constexpr int IN_W = 450;
constexpr int KH = 15, KW = 15;
constexpr int OH = 436, OW = 436;
constexpr int NOUT = OH * OW;   // 190096
constexpr int KSIZE = KH * KW;  // 225

__global__ __launch_bounds__(256)
void lc2d_thread_per_out(const float* __restrict__ x,
                         const float* __restrict__ W,
                         float* __restrict__ out) {
    const int oidx = blockIdx.x * 256 + threadIdx.x;
    if (oidx >= NOUT) return;

    const int oi = oidx / OW;           // magic-mul div
    const int oj = oidx - oi * OW;

    const float* __restrict__ wp = W + (size_t)oidx * KSIZE;
    const float* __restrict__ xp = x + oi * IN_W + oj;

    float sum = 0.0f;
#pragma unroll 3
    for (int kh = 0; kh < KH; ++kh) {
        const float* __restrict__ xr = xp + kh * IN_W;
        const float* __restrict__ wr = wp + kh * KW;
#pragma unroll
        for (int kw = 0; kw < KW; ++kw) {
            sum = fmaf(wr[kw], xr[kw], sum);
        }
    }

    out[oidx] = sum;
}

extern "C" void kernel_launch(void* const* d_in, const int* in_sizes, int n_in,
                              void* d_out, int out_size, void* d_ws, size_t ws_size,
                              hipStream_t stream) {
    const float* x = (const float*)d_in[0];  // (450,450)
    const float* W = (const float*)d_in[1];  // (436,436,15,15)
    float* out = (float*)d_out;              // (436,436)

    const int nblocks = (NOUT + 255) / 256;  // 743
    lc2d_thread_per_out<<<nblocks, 256, 0, stream>>>(x, W, out);
}

// Round 3
// 237.252 us; speedup vs baseline: 1.1231x; 1.1231x over previous
//
#include <hip/hip_runtime.h>

// LocallyConnected2d: out[i,j] = sum_{kh,kw} x[i+kh, j+kw] * W[i,j,kh,kw]
// x: (450,450) f32 (810 KB, cache-resident), W: (436,436,15,15) f32 (171 MB,
// streamed once) -> HBM-bound, floor = 171 MB / 6.9 TB/s ~= 25 us.
//
// R3: wave-per-QUAD (4 consecutive outputs). The quad's W data is 900
// contiguous floats = 225 float4s, 16B-aligned (q*3600 B), so lane l issues
// global_load_dwordx4 at index l+64t (t=0..3, t=3 masked to 33 lanes):
// 1024 B per instruction, perfectly coalesced. 4x payload/wave vs R1
// amortizes addressing + reduction overhead.
//
// Since 436 % 4 == 0, a quad never wraps an output row:
//   out s in quad -> x base = xb0 + s  (s = segment = e/225)
// Element e = 4*lane + 256*t + c; segment boundary inside a lane's float4 is
// one compare: b = (4*lane + c >= 225 - 31*t), seg = t + b -> accumulate into
// acc[t] or acc[t+1] (compile-time register indices).
//   k  = e - 225*seg = 4*lane + c + 31*t - 225*b      (in [0,225))
//   xi = xb0 + seg + k + 435*kh  = xb0 + 4*lane + c + 32*t - 224*b + 435*(k/15)

constexpr int IN_W = 450;
constexpr int KSIZE = 225;      // 15*15
constexpr int OW = 436;
constexpr int NOUT = 436 * 436; // 190096
constexpr int NQUAD = NOUT / 4; // 47524

__global__ __launch_bounds__(256)
void lc2d_quad(const float* __restrict__ x,
               const float* __restrict__ W,
               float* __restrict__ out) {
    const int lane = threadIdx.x & 63;
    const int wave = threadIdx.x >> 6;
    const int q = blockIdx.x * 4 + wave;
    if (q >= NQUAD) return;

    const int o0 = q * 4;                 // first output of the quad
    const int oi = o0 / OW;
    const int oj = o0 - oi * OW;          // multiple of 4, <= 432 -> no row wrap
    const int xb0 = oi * IN_W + oj;

    const float4* __restrict__ W4 = (const float4*)W + (size_t)q * KSIZE;
    const int el4 = lane * 4;

    float acc[4] = {0.f, 0.f, 0.f, 0.f};

    // t = 0,1,2: all 64 lanes active
#pragma unroll
    for (int t = 0; t < 3; ++t) {
        const float4 wq = W4[lane + 64 * t];
        const float wv[4] = {wq.x, wq.y, wq.z, wq.w};
#pragma unroll
        for (int c = 0; c < 4; ++c) {
            const int TH = 225 - 31 * t;
            const bool b = (el4 + c) >= TH;             // crossed into seg t+1
            const unsigned k = (unsigned)(el4 + c + 31 * t - (b ? 225 : 0));
            const int kh = (int)(k / 15u);              // magic-mul, k < 225
            const int xi = xb0 + el4 + c + 32 * t - (b ? 224 : 0) + 435 * kh;
            const float p = wv[c] * x[xi];
            if (b) acc[t + 1] += p; else acc[t] += p;   // static reg indices
        }
    }
    // t = 3: lanes 0..32 only (elements 768..899), all in segment 3
    if (el4 < 132) {
        const float4 wq = W4[lane + 192];
        const float wv[4] = {wq.x, wq.y, wq.z, wq.w};
#pragma unroll
        for (int c = 0; c < 4; ++c) {
            const unsigned k = (unsigned)(el4 + c + 93);
            const int kh = (int)(k / 15u);
            const int xi = xb0 + el4 + c + 96 + 435 * kh;
            acc[3] = fmaf(wv[c], x[xi], acc[3]);
        }
    }

    // 4 butterfly reductions across the 64-lane wave
#pragma unroll
    for (int off = 32; off > 0; off >>= 1) {
        acc[0] += __shfl_xor(acc[0], off, 64);
        acc[1] += __shfl_xor(acc[1], off, 64);
        acc[2] += __shfl_xor(acc[2], off, 64);
        acc[3] += __shfl_xor(acc[3], off, 64);
    }

    if (lane == 0) {
        ((float4*)out)[q] = make_float4(acc[0], acc[1], acc[2], acc[3]);
    }
}

extern "C" void kernel_launch(void* const* d_in, const int* in_sizes, int n_in,
                              void* d_out, int out_size, void* d_ws, size_t ws_size,
                              hipStream_t stream) {
    const float* x = (const float*)d_in[0];  // (450,450)
    const float* W = (const float*)d_in[1];  // (436,436,15,15)
    float* out = (float*)d_out;              // (436,436)

    const int nblocks = (NQUAD + 3) / 4;     // 11881, 4 waves/block
    lc2d_quad<<<nblocks, 256, 0, stream>>>(x, W, out);
}

// Round 4
// 234.395 us; speedup vs baseline: 1.1367x; 1.0122x over previous
//
#include <hip/hip_runtime.h>

// LocallyConnected2d: out[i,j] = sum_{kh,kw} x[i+kh, j+kw] * W[i,j,kh,kw]
// x: (450,450) f32 (810 KB), W: (436,436,15,15) f32 (171 MB, streamed once).
// HBM-bound: floor ~= 171 MB / 6.9 TB/s ~= 25 us.
//
// R4: wave-per-quad with lane->k STRIDE-1 and x via per-wave LDS patch.
//  - R3's x gathers (lane stride 4 over 256 k-values) touched ~25-30 lines
//    per instruction (~400 line-transactions/wave) -> L1/TA line pace was the
//    co-bottleneck. Here x is staged once per wave into a 15x18 LDS patch
//    (~30 line-touches), then read with stride-1 ds_read_b32 (conflict-free;
//    2-way aliasing is free).
//  - W: lane l loads W[q*900 + l + 64t], t=0..13 (+4-elem tail) -> 256 B
//    coalesced per instruction, same total line count as float4 loads.
//  - Segment s = e/225 crosses a lane boundary only at t=3 (lane 33),
//    t=7 (lane 2), t=10 (lane 35) -> compile-time predicated adds into
//    static accumulator registers.
//  - Reduction: 14 shuffles instead of 24 (after the offset-32 butterfly both
//    halves hold pair sums, so acc0/acc1 pack into one lane-split value).

constexpr int IN_W = 450;
constexpr int OW = 436;
constexpr int NQUAD = (436 * 436) / 4;   // 47524 = 11881 blocks * 4 waves, exact

__global__ __launch_bounds__(256, 6)
void lc2d_quad_lds(const float* __restrict__ x,
                   const float* __restrict__ W,
                   float* __restrict__ out) {
    __shared__ float patch[4][270];      // 15 rows x 18 cols per wave, 4.3 KB

    const int lane = threadIdx.x & 63;
    const int wv = threadIdx.x >> 6;
    const int q = blockIdx.x * 4 + wv;   // grid is exact: no bounds check

    const int o0 = q * 4;
    const int oi = o0 / OW;              // magic-mul
    const int oj = o0 - oi * OW;         // multiple of 4 -> quad never wraps row
    const int xb0 = oi * IN_W + oj;

    const float* __restrict__ Wq = W + (size_t)o0 * 225;   // q*900 floats

    // ---- issue W loads (long-pole HBM stream) ----
    float wreg[14];
#pragma unroll
    for (int t = 0; t < 14; ++t) wreg[t] = Wq[lane + 64 * t];
    float wtail = (lane < 4) ? Wq[896 + lane] : 0.0f;

    // ---- stage x patch 15x18 into this wave's LDS slab ----
    float* lp = patch[wv];
#pragma unroll
    for (int p = 0; p < 5; ++p) {
        const int i = lane + 64 * p;     // 0..269 (p=4: lanes 0..13)
        if (p < 4 || i < 270) {
            const unsigned r = (unsigned)i / 18u;   // magic-mul
            const int c = i - (int)r * 18;
            lp[i] = x[xb0 + (int)r * IN_W + c];
        }
    }
    __syncthreads();   // makes cross-lane LDS writes visible (block-uniform)

    // ---- compute: element e = lane + 64t, segment s = e/225 ----
    // Per-t constants: S0 = s of lane 0, BL = first lane in segment S0+1
    // (64 if no crossing), K0 = 64t - 225*S0.
    constexpr int S0[14] = {0,0,0,0, 1,1,1,1, 2,2,2, 3,3,3};
    constexpr int BL[14] = {64,64,64,33, 64,64,64,2, 64,64,35, 64,64,64};
    constexpr int K0[14] = {0,64,128,192, 31,95,159,223, 62,126,190, 29,93,157};

    float acc[4] = {0.f, 0.f, 0.f, 0.f};
#pragma unroll
    for (int t = 0; t < 14; ++t) {
        const bool b = (BL[t] != 64) && (lane >= BL[t]);
        const unsigned k = (unsigned)(lane + K0[t] - (b ? 225 : 0)); // in [0,225)
        const unsigned kh = k / 15u;                                  // magic-mul
        const int addr = (int)(k + 3u * kh) + S0[t] + (b ? 1 : 0);    // kh*18+kw+s
        const float pr = wreg[t] * lp[addr];
        if (BL[t] == 64) {
            acc[S0[t]] += pr;                  // compile-time index
        } else {
            if (b) acc[S0[t] + 1] += pr; else acc[S0[t]] += pr;
        }
    }
    // tail: e = 896..899 on lanes 0..3 -> s=3, k=221..224, kh=14, kw=11..14
    if (lane < 4) {
        acc[3] = fmaf(wtail, lp[266 + lane], acc[3]);  // 14*18 + (kw+3)
    }

    // ---- reduction: 14 shuffles total ----
#pragma unroll
    for (int a = 0; a < 4; ++a) acc[a] += __shfl_xor(acc[a], 32, 64);
    // every lane now holds its {l, l^32} pair sum -> pack two accs per value
    float zA = (lane < 32) ? acc[0] : acc[1];
    float zB = (lane < 32) ? acc[2] : acc[3];
#pragma unroll
    for (int off = 16; off > 0; off >>= 1) {
        zA += __shfl_xor(zA, off, 64);   // stays within each 32-lane half
        zB += __shfl_xor(zB, off, 64);
    }
    if (lane == 0)  { out[o0]     = zA; out[o0 + 2] = zB; }
    if (lane == 32) { out[o0 + 1] = zA; out[o0 + 3] = zB; }
}

extern "C" void kernel_launch(void* const* d_in, const int* in_sizes, int n_in,
                              void* d_out, int out_size, void* d_ws, size_t ws_size,
                              hipStream_t stream) {
    const float* x = (const float*)d_in[0];  // (450,450)
    const float* W = (const float*)d_in[1];  // (436,436,15,15)
    float* out = (float*)d_out;              // (436,436)

    const int nblocks = NQUAD / 4;           // 11881, exact
    lc2d_quad_lds<<<nblocks, 256, 0, stream>>>(x, W, out);
}